// Round 5
// baseline (208.216 us; speedup 1.0000x reference)
//
#include <hip/hip_runtime.h>

typedef __bf16 bf16;
typedef __bf16 bf16x8 __attribute__((ext_vector_type(8)));
typedef float f32x4 __attribute__((ext_vector_type(4)));
typedef unsigned u32x4 __attribute__((ext_vector_type(4)));
typedef unsigned u32;

#define MFMA16(a, b, c) __builtin_amdgcn_mfma_f32_16x16x32_bf16((a), (b), (c), 0, 0, 0)

static __device__ __forceinline__ bf16x8 ldg8(const bf16* p) {
  return *(const bf16x8*)p;
}
static __device__ __forceinline__ unsigned cvt_pk_bf16(float lo, float hi) {
  unsigned d;
  asm("v_cvt_pk_bf16_f32 %0, %1, %2" : "=v"(d) : "v"(lo), "v"(hi));
  return d;
}
static __device__ __forceinline__ void pl32_swap(unsigned& a, unsigned& b) {
  asm("v_permlane32_swap_b32 %0, %1" : "+v"(a), "+v"(b));
}
static __device__ __forceinline__ void pl16_swap(unsigned& a, unsigned& b) {
  asm("v_permlane16_swap_b32 %0, %1" : "+v"(a), "+v"(b));
}
// async DMA global->LDS, 16B/lane; LDS dest = wave-uniform base + lane*16
static __device__ __forceinline__ void async_lds16(const bf16* g, bf16* l) {
  __builtin_amdgcn_global_load_lds(
      (const __attribute__((address_space(1))) u32*)(const void*)g,
      (__attribute__((address_space(3))) u32*)(void*)l, 16, 0, 0);
}

// ===========================================================================
// Ladder: 803 -> ... -> 221 -> 222 (in-reg P) -> 204 (exp2+ones-MFMA+split4,
// flash 83us) -> r3 NaN (half-staged tile) -> r4 206 (flash merged-cluster
// variant REGRESSED 83->93.5; reg-staged 128^2 GEMM only -8.5us: 12 LDS
// ops/wave/kstep = LDS-write+VALU-bound, the m93 operating point).
// r5: (a) flash reverted to the PROVEN r2 version (split4, per-h2 clusters);
// (b) gemm128_core staged via global_load_lds width=16 (m97 pattern: 4 DMA +
// 8 ds_read : 16 MFMA per kstep, one barrier, dbuf prefetch-into-other);
// (c) combine sums 4 partials, emits P32 packing for out_gemm.
// ws overlays (proven r2 layout, ends 60.29MB < 61.4MB).
// ===========================================================================

// ---- pack x (fp32 [8192][512]) into P32 tiles: tile(mt,kc) = 128x32,
// linear unit = kchunk*128 + r (8 bf16 each), tiles at (mt*16+kc)*4096 ----
__global__ __launch_bounds__(256) void cvt_pack_x(const float* __restrict__ x,
                                                  bf16* __restrict__ Xp) {
  int mt = blockIdx.x, kc = blockIdx.y;
  int r = threadIdx.x >> 1;
  int khalf = threadIdx.x & 1;
  const float* src = x + (size_t)(mt * 128 + r) * 512 + kc * 32 + khalf * 16;
  float4 v0 = *(const float4*)(src + 0);
  float4 v1 = *(const float4*)(src + 4);
  float4 v2 = *(const float4*)(src + 8);
  float4 v3 = *(const float4*)(src + 12);
  bf16* tile = Xp + ((size_t)mt * 16 + kc) * 4096;
  bf16x8 a, b;
  a[0] = (bf16)v0.x; a[1] = (bf16)v0.y; a[2] = (bf16)v0.z; a[3] = (bf16)v0.w;
  a[4] = (bf16)v1.x; a[5] = (bf16)v1.y; a[6] = (bf16)v1.z; a[7] = (bf16)v1.w;
  b[0] = (bf16)v2.x; b[1] = (bf16)v2.y; b[2] = (bf16)v2.z; b[3] = (bf16)v2.w;
  b[4] = (bf16)v3.x; b[5] = (bf16)v3.y; b[6] = (bf16)v3.z; b[7] = (bf16)v3.w;
  int kc0 = khalf * 2;
  *(bf16x8*)&tile[(kc0 + 0) * 1024 + r * 8] = a;
  *(bf16x8*)&tile[(kc0 + 1) * 1024 + r * 8] = b;
}

// ---- pack W (fp32 [K][N]) transposed into P32T tiles: tile(nt,kc) holds
// (n,kk) at kchunk*1024 + n*8 + (kk&7); grid (16 kc, N/128 nt) ----
__global__ __launch_bounds__(256) void transpose_pack_w(const float* __restrict__ W,
                                                        bf16* __restrict__ Wp,
                                                        int N) {
  __shared__ float tile[32 * 129];
  int kc = blockIdx.x, nt = blockIdx.y;
  int row = threadIdx.x >> 3;            // 0..31 (k within chunk-of-32)
  int c0 = (threadIdx.x & 7) * 16;       // 16 fp32 per thread
  const float* src = W + (size_t)(kc * 32 + row) * N + nt * 128 + c0;
#pragma unroll
  for (int i = 0; i < 4; i++) {
    float4 v = *(const float4*)(src + i * 4);
    tile[row * 129 + c0 + i * 4 + 0] = v.x;
    tile[row * 129 + c0 + i * 4 + 1] = v.y;
    tile[row * 129 + c0 + i * 4 + 2] = v.z;
    tile[row * 129 + c0 + i * 4 + 3] = v.w;
  }
  __syncthreads();
  bf16* dst = Wp + ((size_t)nt * 16 + kc) * 4096;
#pragma unroll
  for (int half = 0; half < 2; half++) {
    int U = threadIdx.x + half * 256;    // unit = kchunk*128 + n
    int kchunk = U >> 7, n = U & 127;
    bf16x8 o;
#pragma unroll
    for (int j = 0; j < 8; j++) o[j] = (bf16)tile[(kchunk * 8 + j) * 129 + n];
    *(bf16x8*)&dst[U * 8] = o;
  }
}

// ---------------------------------------------------------------------------
// 128x128-tile GEMM core, BK=32, KC=16, 4 waves (2x2 quadrants of 64x64).
// Staging via global_load_lds (m97): per k-step per wave 4 DMA (2 A, 2 B,
// each 64 lanes x 16B = 1KB) + 8 ds_read_b128 + 16 MFMA, ONE barrier.
// Double-buffered: prefetch tile kc+1 into other buffer right at loop top;
// __syncthreads (drains vmcnt0+lgkm0) at end makes it ready. Race-free:
// readers of buf[next] (iter kc-1 frag reads) precede barrier(kc-1).
// Linear LDS layout (unit = kchunk*128 + row) matches DMA's linear dest.
// ---------------------------------------------------------------------------
static __device__ __forceinline__ void stage_tile(const bf16* __restrict__ g,
                                                  bf16* l, int wave, int lane) {
#pragma unroll
  for (int c = 0; c < 2; c++) {
    int chunk = wave * 2 + c;  // 8 chunks of 512 elem cover the 4096-elem tile
    async_lds16(g + chunk * 512 + lane * 8, l + chunk * 512);
  }
}

__device__ __forceinline__ void gemm128_core(const bf16* __restrict__ At,
                                             const bf16* __restrict__ Bt,
                                             bf16* Ab0, bf16* Ab1, bf16* Bb0,
                                             bf16* Bb1, int wave, int lane,
                                             int wr, int wc, int l16, int quad,
                                             f32x4 acc[4][4]) {
  stage_tile(At, Ab0, wave, lane);
  stage_tile(Bt, Bb0, wave, lane);
  __syncthreads();
#pragma unroll 2
  for (int kc = 0; kc < 16; kc++) {
    bf16* Ab = (kc & 1) ? Ab1 : Ab0;
    bf16* Bb = (kc & 1) ? Bb1 : Bb0;
    if (kc < 15) {  // prefetch next tile into the other buffer (in flight
                    // across this step's ds_reads + MFMAs)
      bf16* An = (kc & 1) ? Ab0 : Ab1;
      bf16* Bn = (kc & 1) ? Bb0 : Bb1;
      stage_tile(At + (kc + 1) * 4096, An, wave, lane);
      stage_tile(Bt + (kc + 1) * 4096, Bn, wave, lane);
    }
    bf16x8 af[4], bf[4];
#pragma unroll
    for (int fi = 0; fi < 4; fi++)
      af[fi] = *(const bf16x8*)&Ab[(quad * 128 + wr * 64 + fi * 16 + l16) * 8];
#pragma unroll
    for (int fj = 0; fj < 4; fj++)
      bf[fj] = *(const bf16x8*)&Bb[(quad * 128 + wc * 64 + fj * 16 + l16) * 8];
    __builtin_amdgcn_s_setprio(1);
#pragma unroll
    for (int fi = 0; fi < 4; fi++)
#pragma unroll
      for (int fj = 0; fj < 4; fj++)
        acc[fi][fj] = MFMA16(af[fi], bf[fj], acc[fi][fj]);
    __builtin_amdgcn_s_setprio(0);
    __syncthreads();
  }
}

// ---------------------------------------------------------------------------
// QKV projection, 128x128 tiles. Grid (64 mt, 12 nt). Q pre-scaled by
// 0.125*log2e. Q,K:[bh][n][d]; V tiled [bh][n>>6][d][n&63].
// ---------------------------------------------------------------------------
__global__ __launch_bounds__(256, 3) void qkv_gemm(const bf16* __restrict__ Xp,
                                                   const bf16* __restrict__ Wp1,
                                                   const float* __restrict__ bqkv,
                                                   bf16* __restrict__ Q,
                                                   bf16* __restrict__ Kh,
                                                   bf16* __restrict__ Vt) {
  int mt = blockIdx.x, nt = blockIdx.y;
  int tid = threadIdx.x;
  int wave = tid >> 6, lane = tid & 63;
  int l16 = lane & 15, quad = lane >> 4;
  int wr = wave >> 1, wc = wave & 1;

  __shared__ __align__(16) bf16 Ab[2][4096];
  __shared__ __align__(16) bf16 Bb[2][4096];

  f32x4 acc[4][4] = {};
  gemm128_core(Xp + (size_t)mt * 16 * 4096, Wp1 + (size_t)nt * 16 * 4096,
               Ab[0], Ab[1], Bb[0], Bb[1], wave, lane, wr, wc, l16, quad, acc);

#pragma unroll
  for (int fj = 0; fj < 4; fj++) {
    int c = nt * 128 + wc * 64 + fj * 16 + l16;
    float bias = bqkv[c];
    int which = c >> 9, inner = c & 511;
    int h = inner >> 6, d = inner & 63;
#pragma unroll
    for (int fi = 0; fi < 4; fi++) {
#pragma unroll
      for (int r = 0; r < 4; r++) {
        int m = mt * 128 + wr * 64 + fi * 16 + quad * 4 + r;
        int b = m >> 12, n = m & 4095;
        int bh = b * 8 + h;
        float v = acc[fi][fj][r] + bias;
        if (which == 0)
          Q[((size_t)bh * 4096 + n) * 64 + d] = (bf16)(v * 0.18033688f);
        else if (which == 1)
          Kh[((size_t)bh * 4096 + n) * 64 + d] = (bf16)v;
        else
          Vt[(((size_t)bh * 64 + (n >> 6)) * 64 + d) * 64 + (n & 63)] = (bf16)v;
      }
    }
  }
}

// ---------------------------------------------------------------------------
// flash_partial (r2-proven, 83us): grid (32 strip128, 16 bh, 4 quarter),
// block 256 = 4 waves, 32 Q rows/wave, 16 KV-tiles of 64. Per-h2 phase
// clusters: QK(8 MFMA) -> SM -> PV+l(10 MFMA). Swapped QK^T -> in-reg P
// (cvt_pk + permlane32/16), exp2 (scale folded into Q), ones-MFMA rowsum
// (shuffle-free Lpart). K/V dbuf, ONE barrier/tile, reg-prefetch after it.
// ---------------------------------------------------------------------------
__global__ __launch_bounds__(256, 4) void flash_partial(const bf16* __restrict__ Q,
                                                        const bf16* __restrict__ K,
                                                        const bf16* __restrict__ Vt,
                                                        bf16* __restrict__ Opart,
                                                        float* __restrict__ Lpart) {
  int strip = blockIdx.x, bh = blockIdx.y, qtr = blockIdx.z;
  int tid = threadIdx.x;
  int wave = tid >> 6, lane = tid & 63;
  int l16 = lane & 15, quad = lane >> 4;

  const bf16* Qh = Q + (size_t)bh * 4096 * 64;
  const bf16* Kg = K + ((size_t)bh * 4096 + qtr * 1024) * 64;
  const bf16* Vg = Vt + (size_t)bh * 64 * 4096 + (size_t)qtr * 1024 * 64;

  __shared__ __align__(16) bf16 Klds[2][4096];
  __shared__ __align__(16) bf16 Vlds[2][4096];

  int qbase = strip * 128 + wave * 32;
  bf16x8 aq[2][2];
#pragma unroll
  for (int mt = 0; mt < 2; mt++) {
    const bf16* qr = Qh + (size_t)(qbase + mt * 16 + l16) * 64;
    aq[mt][0] = ldg8(qr + quad * 8);
    aq[mt][1] = ldg8(qr + 32 + quad * 8);
  }

  bf16x8 ones;
#pragma unroll
  for (int i = 0; i < 8; i++) ones[i] = (bf16)1.0f;

  f32x4 o[2][4] = {};
  f32x4 acc_l[2] = {};

  int e0 = tid * 8, e1 = (256 + tid) * 8;
  int r0 = e0 >> 6, r1 = e1 >> 6;
  int u0 = r0 * 8 + (((e0 & 63) >> 3) ^ (r0 & 7));
  int u1 = r1 * 8 + (((e1 & 63) >> 3) ^ (r1 & 7));

  bf16x8 kp0 = ldg8(Kg + e0), kp1 = ldg8(Kg + e1);
  bf16x8 vp0 = ldg8(Vg + e0), vp1 = ldg8(Vg + e1);

#pragma unroll 2
  for (int t = 0; t < 16; t++) {
    int cur = t & 1;
    bf16* kl = Klds[cur];
    bf16* vl = Vlds[cur];
    *(bf16x8*)&kl[u0 * 8] = kp0;
    *(bf16x8*)&kl[u1 * 8] = kp1;
    *(bf16x8*)&vl[u0 * 8] = vp0;
    *(bf16x8*)&vl[u1 * 8] = vp1;
    __syncthreads();

    if (t < 15) {
      const bf16* kg = Kg + (size_t)(t + 1) * 4096;
      const bf16* vg = Vg + (size_t)(t + 1) * 4096;
      kp0 = ldg8(kg + e0);
      kp1 = ldg8(kg + e1);
      vp0 = ldg8(vg + e0);
      vp1 = ldg8(vg + e1);
    }

#pragma unroll
    for (int h2 = 0; h2 < 2; h2++) {  // two 32-kv halves of the 64-kv tile
      // ---- S^T = K Q^T (swapped operands) ----
      f32x4 s[2][2] = {};
      __builtin_amdgcn_s_setprio(1);
#pragma unroll
      for (int c2 = 0; c2 < 2; c2++) {
        int n = h2 * 32 + c2 * 16 + l16;  // kv row
        bf16x8 k0 = *(const bf16x8*)&kl[(n * 8 + (quad ^ (n & 7))) * 8];
        bf16x8 k1 = *(const bf16x8*)&kl[(n * 8 + ((4 + quad) ^ (n & 7))) * 8];
#pragma unroll
        for (int mt = 0; mt < 2; mt++) {
          s[mt][c2] = MFMA16(k0, aq[mt][0], s[mt][c2]);
          s[mt][c2] = MFMA16(k1, aq[mt][1], s[mt][c2]);
        }
      }
      __builtin_amdgcn_s_setprio(0);

      // ---- p = exp2(s) (log2e pre-folded); pack+redistribute to A-frags ----
      bf16x8 pa[2];
#pragma unroll
      for (int mt = 0; mt < 2; mt++) {
        unsigned ue[2], wo[2];
#pragma unroll
        for (int c2 = 0; c2 < 2; c2++) {
          float p0 = __builtin_amdgcn_exp2f(s[mt][c2][0]);
          float p1 = __builtin_amdgcn_exp2f(s[mt][c2][1]);
          float p2 = __builtin_amdgcn_exp2f(s[mt][c2][2]);
          float p3 = __builtin_amdgcn_exp2f(s[mt][c2][3]);
          ue[c2] = cvt_pk_bf16(p0, p1);  // kv = base+0,1
          wo[c2] = cvt_pk_bf16(p2, p3);  // kv = base+2,3
        }
        pl32_swap(ue[0], ue[1]);
        pl16_swap(ue[0], ue[1]);  // ue[0]=D0 (kv q'*8+0,1), ue[1]=D2 (+4,5)
        pl32_swap(wo[0], wo[1]);
        pl16_swap(wo[0], wo[1]);  // wo[0]=D1 (+2,3),        wo[1]=D3 (+6,7)
        u32x4 pk = {ue[0], wo[0], ue[1], wo[1]};
        pa[mt] = __builtin_bit_cast(bf16x8, pk);
      }

      // ---- O += P V; l += P ones (rowsum on matrix pipe) ----
      __builtin_amdgcn_s_setprio(1);
      acc_l[0] = MFMA16(pa[0], ones, acc_l[0]);
      acc_l[1] = MFMA16(pa[1], ones, acc_l[1]);
#pragma unroll
      for (int ct = 0; ct < 4; ct++) {
        int d = ct * 16 + l16;
        bf16x8 bv = *(const bf16x8*)&vl[(d * 8 + ((h2 * 4 + quad) ^ (d & 7))) * 8];
        o[0][ct] = MFMA16(pa[0], bv, o[0][ct]);
        o[1][ct] = MFMA16(pa[1], bv, o[1][ct]);
      }
      __builtin_amdgcn_s_setprio(0);
    }
  }

  // ---- epilogue: partial o (bf16) + l (fp32, shuffle-free) ----
  size_t ub = ((size_t)qtr * 16 + bh) * 32 + strip;
  bf16* op = Opart + ub * 8192;
#pragma unroll
  for (int mt = 0; mt < 2; mt++) {
#pragma unroll
    for (int ct = 0; ct < 4; ct++)
#pragma unroll
      for (int r = 0; r < 4; r++)
        op[(wave * 32 + mt * 16 + quad * 4 + r) * 64 + ct * 16 + l16] =
            (bf16)o[mt][ct][r];
    if (l16 == 0) {
#pragma unroll
      for (int r = 0; r < 4; r++)
        Lpart[ub * 128 + wave * 32 + mt * 16 + quad * 4 + r] = acc_l[mt][r];
    }
  }
}

// ---------------------------------------------------------------------------
// flash_combine: Ap(P32-packed for out_gemm) = sum_q(o_q) / sum_q(l_q).
// Grid (64 mt, 16 kc); block per output tile(mt,kc) of 128x32.
// ---------------------------------------------------------------------------
__global__ __launch_bounds__(256) void flash_combine(const bf16* __restrict__ Opart,
                                                     const float* __restrict__ Lpart,
                                                     bf16* __restrict__ Ap) {
  int mt = blockIdx.x, kc = blockIdx.y;
  int b = mt >> 5, strip = mt & 31;
  int h = kc >> 1, d0 = (kc & 1) * 32;
  int bh = b * 8 + h;
  size_t u[4];
#pragma unroll
  for (int q = 0; q < 4; q++) u[q] = ((size_t)q * 16 + bh) * 32 + strip;
  bf16* dst = Ap + ((size_t)mt * 16 + kc) * 4096;
#pragma unroll
  for (int hf = 0; hf < 2; hf++) {
    int U = threadIdx.x + hf * 256;  // unit = kchunk*128 + r
    int kchunk = U >> 7, r = U & 127;
    float acc[8] = {};
    float ls = 0.f;
#pragma unroll
    for (int q = 0; q < 4; q++) {
      bf16x8 ov = ldg8(&Opart[u[q] * 8192 + r * 64 + d0 + kchunk * 8]);
#pragma unroll
      for (int j = 0; j < 8; j++) acc[j] += (float)ov[j];
      ls += Lpart[u[q] * 128 + r];
    }
    float rl = 1.0f / ls;
    bf16x8 o;
#pragma unroll
    for (int j = 0; j < 8; j++) o[j] = (bf16)(acc[j] * rl);
    *(bf16x8*)&dst[U * 8] = o;
  }
}

// ---------------------------------------------------------------------------
// Output projection, 128x128 tiles: Ap(P32) @ Wp2(P32T) + bias -> FP32.
// Grid (64 mt, 4 nt).
// ---------------------------------------------------------------------------
__global__ __launch_bounds__(256, 3) void out_gemm(const bf16* __restrict__ Ap,
                                                   const bf16* __restrict__ Wp2,
                                                   const float* __restrict__ bout,
                                                   float* __restrict__ Out) {
  int mt = blockIdx.x, nt = blockIdx.y;
  int tid = threadIdx.x;
  int wave = tid >> 6, lane = tid & 63;
  int l16 = lane & 15, quad = lane >> 4;
  int wr = wave >> 1, wc = wave & 1;

  __shared__ __align__(16) bf16 Ab[2][4096];
  __shared__ __align__(16) bf16 Bb[2][4096];

  f32x4 acc[4][4] = {};
  gemm128_core(Ap + (size_t)mt * 16 * 4096, Wp2 + (size_t)nt * 16 * 4096,
               Ab[0], Ab[1], Bb[0], Bb[1], wave, lane, wr, wc, l16, quad, acc);

#pragma unroll
  for (int fj = 0; fj < 4; fj++) {
    int c = nt * 128 + wc * 64 + fj * 16 + l16;
    float bias = bout[c];
#pragma unroll
    for (int fi = 0; fi < 4; fi++) {
#pragma unroll
      for (int r = 0; r < 4; r++) {
        int m = mt * 128 + wr * 64 + fi * 16 + quad * 4 + r;
        Out[(size_t)m * 512 + c] = acc[fi][fj][r] + bias;
      }
    }
  }
}

// ---------------------------------------------------------------------------
// ws layout (lifetime-overlapped; end 60,293,120 < 61.4MB):
//   Q 0 (8.39M) | K 8388608 | Vt 16777216 | Wp2 25165824 (0.52M) |
//   Opart 25690112 (33.55M) | Lpart 59244544 (1.05M)
//   Xp 25690112 (8.39M, dead after qkv) | Wp1 34078720 (1.57M, dead after
//   qkv) | Ap 0 (overlays Q, dead post-flash; written by combine)
// ---------------------------------------------------------------------------
extern "C" void kernel_launch(void* const* d_in, const int* in_sizes, int n_in,
                              void* d_out, int out_size, void* d_ws,
                              size_t ws_size, hipStream_t stream) {
  const float* x = (const float*)d_in[0];
  const float* w_qkv = (const float*)d_in[1];
  const float* b_qkv = (const float*)d_in[2];
  const float* w_out = (const float*)d_in[3];
  const float* b_out = (const float*)d_in[4];
  float* out = (float*)d_out;

  char* ws = (char*)d_ws;
  bf16* Q = (bf16*)(ws + 0);
  bf16* K = (bf16*)(ws + 8388608);
  bf16* Vt = (bf16*)(ws + 16777216);
  bf16* Wp2 = (bf16*)(ws + 25165824);
  bf16* Opart = (bf16*)(ws + 25690112);
  float* Lpart = (float*)(ws + 59244544);
  bf16* Xp = (bf16*)(ws + 25690112);   // overlays Opart region, dead pre-flash
  bf16* Wp1 = (bf16*)(ws + 34078720);  // overlays Opart region, dead pre-flash
  bf16* Ap = (bf16*)(ws + 0);          // overlays Q, dead post-flash

  cvt_pack_x<<<dim3(64, 16), 256, 0, stream>>>(x, Xp);
  transpose_pack_w<<<dim3(16, 12), 256, 0, stream>>>(w_qkv, Wp1, 1536);
  transpose_pack_w<<<dim3(16, 4), 256, 0, stream>>>(w_out, Wp2, 512);
  qkv_gemm<<<dim3(64, 12), 256, 0, stream>>>(Xp, Wp1, b_qkv, Q, K, Vt);
  flash_partial<<<dim3(32, 16, 4), 256, 0, stream>>>(Q, K, Vt, Opart, Lpart);
  flash_combine<<<dim3(64, 16), 256, 0, stream>>>(Opart, Lpart, Ap);
  out_gemm<<<dim3(64, 4), 256, 0, stream>>>(Ap, Wp2, b_out, out);
}

// Round 6
// 197.595 us; speedup vs baseline: 1.0538x; 1.0538x over previous
//
#include <hip/hip_runtime.h>

typedef __bf16 bf16;
typedef __bf16 bf16x8 __attribute__((ext_vector_type(8)));
typedef float f32x4 __attribute__((ext_vector_type(4)));
typedef unsigned u32x4 __attribute__((ext_vector_type(4)));

#define MFMA16(a, b, c) __builtin_amdgcn_mfma_f32_16x16x32_bf16((a), (b), (c), 0, 0, 0)

static __device__ __forceinline__ bf16x8 ldg8(const bf16* p) {
  return *(const bf16x8*)p;
}
static __device__ __forceinline__ unsigned cvt_pk_bf16(float lo, float hi) {
  unsigned d;
  asm("v_cvt_pk_bf16_f32 %0, %1, %2" : "=v"(d) : "v"(lo), "v"(hi));
  return d;
}
static __device__ __forceinline__ void pl32_swap(unsigned& a, unsigned& b) {
  asm("v_permlane32_swap_b32 %0, %1" : "+v"(a), "+v"(b));
}
static __device__ __forceinline__ void pl16_swap(unsigned& a, unsigned& b) {
  asm("v_permlane16_swap_b32 %0, %1" : "+v"(a), "+v"(b));
}

// ===========================================================================
// Ladder: 803 -> ... -> 204 (flash 83) -> r4 206 (reg-staged 128^2 GEMM,
// others 113) -> r5 208 (gload_lds GEMM REGRESSED others to 124; flash
// re-proven 83.8). r6 theory: qkv epilogue was the hidden cost -- V stored
// as 16 scattered 2B stores/thread (~128MB effective), Q/K as 32B segments.
// This round: (1) qkv epilogue LDS round-trip -> ALL stores coalesced 16B
// (Q/K: T[row][d] stride-72; V: transposed T[col][n&63], 2 phases over
// n-blocks); (2) cvt_pack_x fused into qkv A-staging (direct fp32 x, conv
// in-reg); (3) both weight packs merged into one launch; (4) GEMM core =
// r4 reg-staged (proven faster than gload_lds here). 5 dispatches.
// flash untouched (r2/r5-proven). ws overlays end 60.29MB < 61.4MB.
// ===========================================================================

// ---- pack W (fp32 [K][N]) transposed into P32T tiles: tile(nt,kc) holds
// (n,kk) at kchunk*1024 + n*8 + (kk&7). Grid (16 kc, 16 nt): nt<12 -> Wqkv
// (N=1536) else Wout (N=512, nt-12). ----
__global__ __launch_bounds__(256) void pack_weights(const float* __restrict__ Wqkv,
                                                    const float* __restrict__ Wout,
                                                    bf16* __restrict__ Wp1,
                                                    bf16* __restrict__ Wp2) {
  __shared__ float tile[32 * 129];
  int kc = blockIdx.x, nt = blockIdx.y;
  const float* W;
  bf16* dst;
  int N, ntl;
  if (nt < 12) {
    W = Wqkv; N = 1536; ntl = nt;
    dst = Wp1 + ((size_t)ntl * 16 + kc) * 4096;
  } else {
    W = Wout; N = 512; ntl = nt - 12;
    dst = Wp2 + ((size_t)ntl * 16 + kc) * 4096;
  }
  int row = threadIdx.x >> 3;
  int c0 = (threadIdx.x & 7) * 16;
  const float* src = W + (size_t)(kc * 32 + row) * N + ntl * 128 + c0;
#pragma unroll
  for (int i = 0; i < 4; i++) {
    float4 v = *(const float4*)(src + i * 4);
    tile[row * 129 + c0 + i * 4 + 0] = v.x;
    tile[row * 129 + c0 + i * 4 + 1] = v.y;
    tile[row * 129 + c0 + i * 4 + 2] = v.z;
    tile[row * 129 + c0 + i * 4 + 3] = v.w;
  }
  __syncthreads();
#pragma unroll
  for (int half = 0; half < 2; half++) {
    int U = threadIdx.x + half * 256;
    int kchunk = U >> 7, n = U & 127;
    bf16x8 o;
#pragma unroll
    for (int j = 0; j < 8; j++) o[j] = (bf16)tile[(kchunk * 8 + j) * 129 + n];
    *(bf16x8*)&dst[U * 8] = o;
  }
}

// ---------------------------------------------------------------------------
// QKV projection, 128x128 tiles, A staged DIRECTLY from fp32 x (convert
// in-reg). Grid (64 mt, 12 nt): nt 0-3 Q, 4-7 K, 8-11 V (block-uniform).
// r4-proven one-barrier reg-staged dbuf: write(cur); sync; prefetch(next);
// frag-read(cur); MFMA. Epilogue: LDS round-trip (reuse 32KB staging SM)
// so every global store is a coalesced 16B bf16x8:
//   Q/K: T[m'][d'] stride 72 (write conflict-free, rows 144B = 16B-aligned),
//        phase ph = wc = head half; store Q/K[(bh*4096+n)*64 + d] rows.
//   V:   T[c'][m''] stride 72 (transpose; ~4-way write conflict, cheap),
//        phase ph = wr = n-block half; store Vt[bh][nb][d][n&63] rows.
// Q pre-scaled by 0.125*log2e (exp2 softmax downstream).
// ---------------------------------------------------------------------------
__global__ __launch_bounds__(256, 3) void qkv_gemm(const float* __restrict__ x,
                                                   const bf16* __restrict__ Wp1,
                                                   const float* __restrict__ bqkv,
                                                   bf16* __restrict__ Q,
                                                   bf16* __restrict__ Kh,
                                                   bf16* __restrict__ Vt) {
  int mt = blockIdx.x, nt = blockIdx.y;
  int tid = threadIdx.x;
  int wave = tid >> 6, lane = tid & 63;
  int l16 = lane & 15, quad = lane >> 4;
  int wr = wave >> 1, wc = wave & 1;

  __shared__ __align__(16) bf16 SM[16384];  // Ab0|Ab1|Bb0|Bb1, epilogue T

  int r = tid >> 1, khalf = tid & 1;
  const float* xs = x + (size_t)(mt * 128 + r) * 512 + khalf * 16;
  const bf16* Bt = Wp1 + (size_t)nt * 16 * 4096;
  int lwA0 = ((khalf * 2 + 0) * 128 + r) * 8;
  int lwA1 = ((khalf * 2 + 1) * 128 + r) * 8;

  float4 fa0 = *(const float4*)(xs + 0);
  float4 fa1 = *(const float4*)(xs + 4);
  float4 fa2 = *(const float4*)(xs + 8);
  float4 fa3 = *(const float4*)(xs + 12);
  bf16x8 pb0 = ldg8(Bt + tid * 8), pb1 = ldg8(Bt + 2048 + tid * 8);

  f32x4 acc[4][4] = {};
#pragma unroll 2
  for (int kc = 0; kc < 16; kc++) {
    bf16* A = SM + (kc & 1) * 4096;
    bf16* B = SM + 8192 + (kc & 1) * 4096;
    bf16x8 a0, a1;
    a0[0] = (bf16)fa0.x; a0[1] = (bf16)fa0.y; a0[2] = (bf16)fa0.z; a0[3] = (bf16)fa0.w;
    a0[4] = (bf16)fa1.x; a0[5] = (bf16)fa1.y; a0[6] = (bf16)fa1.z; a0[7] = (bf16)fa1.w;
    a1[0] = (bf16)fa2.x; a1[1] = (bf16)fa2.y; a1[2] = (bf16)fa2.z; a1[3] = (bf16)fa2.w;
    a1[4] = (bf16)fa3.x; a1[5] = (bf16)fa3.y; a1[6] = (bf16)fa3.z; a1[7] = (bf16)fa3.w;
    *(bf16x8*)&A[lwA0] = a0;
    *(bf16x8*)&A[lwA1] = a1;
    *(bf16x8*)&B[tid * 8] = pb0;
    *(bf16x8*)&B[2048 + tid * 8] = pb1;
    __syncthreads();
    if (kc < 15) {
      const float* xn = xs + (kc + 1) * 32;
      fa0 = *(const float4*)(xn + 0);
      fa1 = *(const float4*)(xn + 4);
      fa2 = *(const float4*)(xn + 8);
      fa3 = *(const float4*)(xn + 12);
      const bf16* bn = Bt + (kc + 1) * 4096;
      pb0 = ldg8(bn + tid * 8);
      pb1 = ldg8(bn + 2048 + tid * 8);
    }
    bf16x8 af[4], bfr[4];
#pragma unroll
    for (int fi = 0; fi < 4; fi++)
      af[fi] = *(const bf16x8*)&A[(quad * 128 + wr * 64 + fi * 16 + l16) * 8];
#pragma unroll
    for (int fj = 0; fj < 4; fj++)
      bfr[fj] = *(const bf16x8*)&B[(quad * 128 + wc * 64 + fj * 16 + l16) * 8];
    __builtin_amdgcn_s_setprio(1);
#pragma unroll
    for (int fi = 0; fi < 4; fi++)
#pragma unroll
      for (int fj = 0; fj < 4; fj++)
        acc[fi][fj] = MFMA16(af[fi], bfr[fj], acc[fi][fj]);
    __builtin_amdgcn_s_setprio(0);
  }

  // ---- epilogue: LDS round-trip, coalesced 16B stores ----
  __syncthreads();  // all frag reads done before SM reuse
  const int TS = 72;  // row stride (elems): 144B = 16B-aligned, low-conflict
  int b = mt >> 5;

  if (nt < 8) {
    // Q (nt<4) or K: layout [bh][n][d], d' = fj*16+l16 in [0,64)
    bool isQ = nt < 4;
    bf16* dstb = isQ ? Q : Kh;
    int hb = isQ ? nt * 2 : (nt - 4) * 2;
#pragma unroll
    for (int ph = 0; ph < 2; ph++) {
      if (wc == ph) {
#pragma unroll
        for (int fj = 0; fj < 4; fj++) {
          float bias = bqkv[nt * 128 + wc * 64 + fj * 16 + l16];
#pragma unroll
          for (int fi = 0; fi < 4; fi++)
#pragma unroll
            for (int rr = 0; rr < 4; rr++) {
              float v = acc[fi][fj][rr] + bias;
              if (isQ) v *= 0.18033688f;  // 0.125*log2e
              SM[(wr * 64 + fi * 16 + quad * 4 + rr) * TS + fj * 16 + l16] =
                  (bf16)v;
            }
        }
      }
      __syncthreads();
      int bh = b * 8 + hb + ph;
      bf16* dh = dstb + (size_t)bh * 4096 * 64 + (size_t)((mt & 31) * 128) * 64;
#pragma unroll
      for (int i = 0; i < 4; i++) {
        int U = tid + i * 256;  // 1024 octets = 128 rows x 8
        int mr = U >> 3, oct = U & 7;
        bf16x8 v = ldg8(&SM[mr * TS + oct * 8]);
        *(bf16x8*)&dh[(size_t)mr * 64 + oct * 8] = v;
      }
      __syncthreads();
    }
  } else {
    // V: layout [bh][nb][d][n&63]; transpose via T[c'][m''], phase = wr
    int h0 = (nt - 8) * 2;
#pragma unroll
    for (int ph = 0; ph < 2; ph++) {
      if (wr == ph) {
#pragma unroll
        for (int fj = 0; fj < 4; fj++) {
          float bias = bqkv[nt * 128 + wc * 64 + fj * 16 + l16];
          int cp = wc * 64 + fj * 16 + l16;
#pragma unroll
          for (int fi = 0; fi < 4; fi++)
#pragma unroll
            for (int rr = 0; rr < 4; rr++)
              SM[cp * TS + fi * 16 + quad * 4 + rr] =
                  (bf16)(acc[fi][fj][rr] + bias);
        }
      }
      __syncthreads();
      int nb = (mt & 31) * 2 + ph;
#pragma unroll
      for (int i = 0; i < 4; i++) {
        int U = tid + i * 256;  // 1024 octets = 128 c' x 8
        int cp = U >> 3, oct = U & 7;
        int h = h0 + (cp >> 6), d = cp & 63;
        int bh = b * 8 + h;
        bf16x8 v = ldg8(&SM[cp * TS + oct * 8]);
        *(bf16x8*)&Vt[(((size_t)bh * 64 + nb) * 64 + d) * 64 + oct * 8] = v;
      }
      __syncthreads();
    }
  }
}

// ---------------------------------------------------------------------------
// flash_partial (r2/r5-proven, 83.8us): grid (32 strip128, 16 bh, 4 qtr),
// 4 waves, 32 Q rows/wave, 16 KV-tiles of 64. Per-h2 clusters: QK(8 MFMA)
// -> SM -> PV+l(10 MFMA). In-reg P (cvt_pk+permlane), exp2, ones-MFMA
// rowsum. K/V dbuf, ONE barrier/tile, reg-prefetch after barrier.
// ---------------------------------------------------------------------------
__global__ __launch_bounds__(256, 4) void flash_partial(const bf16* __restrict__ Q,
                                                        const bf16* __restrict__ K,
                                                        const bf16* __restrict__ Vt,
                                                        bf16* __restrict__ Opart,
                                                        float* __restrict__ Lpart) {
  int strip = blockIdx.x, bh = blockIdx.y, qtr = blockIdx.z;
  int tid = threadIdx.x;
  int wave = tid >> 6, lane = tid & 63;
  int l16 = lane & 15, quad = lane >> 4;

  const bf16* Qh = Q + (size_t)bh * 4096 * 64;
  const bf16* Kg = K + ((size_t)bh * 4096 + qtr * 1024) * 64;
  const bf16* Vg = Vt + (size_t)bh * 64 * 4096 + (size_t)qtr * 1024 * 64;

  __shared__ __align__(16) bf16 Klds[2][4096];
  __shared__ __align__(16) bf16 Vlds[2][4096];

  int qbase = strip * 128 + wave * 32;
  bf16x8 aq[2][2];
#pragma unroll
  for (int mt = 0; mt < 2; mt++) {
    const bf16* qr = Qh + (size_t)(qbase + mt * 16 + l16) * 64;
    aq[mt][0] = ldg8(qr + quad * 8);
    aq[mt][1] = ldg8(qr + 32 + quad * 8);
  }

  bf16x8 ones;
#pragma unroll
  for (int i = 0; i < 8; i++) ones[i] = (bf16)1.0f;

  f32x4 o[2][4] = {};
  f32x4 acc_l[2] = {};

  int e0 = tid * 8, e1 = (256 + tid) * 8;
  int r0 = e0 >> 6, r1 = e1 >> 6;
  int u0 = r0 * 8 + (((e0 & 63) >> 3) ^ (r0 & 7));
  int u1 = r1 * 8 + (((e1 & 63) >> 3) ^ (r1 & 7));

  bf16x8 kp0 = ldg8(Kg + e0), kp1 = ldg8(Kg + e1);
  bf16x8 vp0 = ldg8(Vg + e0), vp1 = ldg8(Vg + e1);

#pragma unroll 2
  for (int t = 0; t < 16; t++) {
    int cur = t & 1;
    bf16* kl = Klds[cur];
    bf16* vl = Vlds[cur];
    *(bf16x8*)&kl[u0 * 8] = kp0;
    *(bf16x8*)&kl[u1 * 8] = kp1;
    *(bf16x8*)&vl[u0 * 8] = vp0;
    *(bf16x8*)&vl[u1 * 8] = vp1;
    __syncthreads();

    if (t < 15) {
      const bf16* kg = Kg + (size_t)(t + 1) * 4096;
      const bf16* vg = Vg + (size_t)(t + 1) * 4096;
      kp0 = ldg8(kg + e0);
      kp1 = ldg8(kg + e1);
      vp0 = ldg8(vg + e0);
      vp1 = ldg8(vg + e1);
    }

#pragma unroll
    for (int h2 = 0; h2 < 2; h2++) {
      f32x4 s[2][2] = {};
      __builtin_amdgcn_s_setprio(1);
#pragma unroll
      for (int c2 = 0; c2 < 2; c2++) {
        int n = h2 * 32 + c2 * 16 + l16;
        bf16x8 k0 = *(const bf16x8*)&kl[(n * 8 + (quad ^ (n & 7))) * 8];
        bf16x8 k1 = *(const bf16x8*)&kl[(n * 8 + ((4 + quad) ^ (n & 7))) * 8];
#pragma unroll
        for (int mt = 0; mt < 2; mt++) {
          s[mt][c2] = MFMA16(k0, aq[mt][0], s[mt][c2]);
          s[mt][c2] = MFMA16(k1, aq[mt][1], s[mt][c2]);
        }
      }
      __builtin_amdgcn_s_setprio(0);

      bf16x8 pa[2];
#pragma unroll
      for (int mt = 0; mt < 2; mt++) {
        unsigned ue[2], wo[2];
#pragma unroll
        for (int c2 = 0; c2 < 2; c2++) {
          float p0 = __builtin_amdgcn_exp2f(s[mt][c2][0]);
          float p1 = __builtin_amdgcn_exp2f(s[mt][c2][1]);
          float p2 = __builtin_amdgcn_exp2f(s[mt][c2][2]);
          float p3 = __builtin_amdgcn_exp2f(s[mt][c2][3]);
          ue[c2] = cvt_pk_bf16(p0, p1);
          wo[c2] = cvt_pk_bf16(p2, p3);
        }
        pl32_swap(ue[0], ue[1]);
        pl16_swap(ue[0], ue[1]);
        pl32_swap(wo[0], wo[1]);
        pl16_swap(wo[0], wo[1]);
        u32x4 pk = {ue[0], wo[0], ue[1], wo[1]};
        pa[mt] = __builtin_bit_cast(bf16x8, pk);
      }

      __builtin_amdgcn_s_setprio(1);
      acc_l[0] = MFMA16(pa[0], ones, acc_l[0]);
      acc_l[1] = MFMA16(pa[1], ones, acc_l[1]);
#pragma unroll
      for (int ct = 0; ct < 4; ct++) {
        int d = ct * 16 + l16;
        bf16x8 bv = *(const bf16x8*)&vl[(d * 8 + ((h2 * 4 + quad) ^ (d & 7))) * 8];
        o[0][ct] = MFMA16(pa[0], bv, o[0][ct]);
        o[1][ct] = MFMA16(pa[1], bv, o[1][ct]);
      }
      __builtin_amdgcn_s_setprio(0);
    }
  }

  size_t ub = ((size_t)qtr * 16 + bh) * 32 + strip;
  bf16* op = Opart + ub * 8192;
#pragma unroll
  for (int mt = 0; mt < 2; mt++) {
#pragma unroll
    for (int ct = 0; ct < 4; ct++)
#pragma unroll
      for (int r = 0; r < 4; r++)
        op[(wave * 32 + mt * 16 + quad * 4 + r) * 64 + ct * 16 + l16] =
            (bf16)o[mt][ct][r];
    if (l16 == 0) {
#pragma unroll
      for (int r = 0; r < 4; r++)
        Lpart[ub * 128 + wave * 32 + mt * 16 + quad * 4 + r] = acc_l[mt][r];
    }
  }
}

// ---------------------------------------------------------------------------
// flash_combine: Ap(P32-packed) = sum_q(o_q) / sum_q(l_q). Grid (64 mt, 16 kc).
// ---------------------------------------------------------------------------
__global__ __launch_bounds__(256) void flash_combine(const bf16* __restrict__ Opart,
                                                     const float* __restrict__ Lpart,
                                                     bf16* __restrict__ Ap) {
  int mt = blockIdx.x, kc = blockIdx.y;
  int b = mt >> 5, strip = mt & 31;
  int h = kc >> 1, d0 = (kc & 1) * 32;
  int bh = b * 8 + h;
  size_t u[4];
#pragma unroll
  for (int q = 0; q < 4; q++) u[q] = ((size_t)q * 16 + bh) * 32 + strip;
  bf16* dst = Ap + ((size_t)mt * 16 + kc) * 4096;
#pragma unroll
  for (int hf = 0; hf < 2; hf++) {
    int U = threadIdx.x + hf * 256;
    int kchunk = U >> 7, r = U & 127;
    float acc[8] = {};
    float ls = 0.f;
#pragma unroll
    for (int q = 0; q < 4; q++) {
      bf16x8 ov = ldg8(&Opart[u[q] * 8192 + r * 64 + d0 + kchunk * 8]);
#pragma unroll
      for (int j = 0; j < 8; j++) acc[j] += (float)ov[j];
      ls += Lpart[u[q] * 128 + r];
    }
    float rl = 1.0f / ls;
    bf16x8 o;
#pragma unroll
    for (int j = 0; j < 8; j++) o[j] = (bf16)(acc[j] * rl);
    *(bf16x8*)&dst[U * 8] = o;
  }
}

// ---------------------------------------------------------------------------
// Output projection, 128x128 tiles, r4-proven reg-staged core:
// Ap(P32) @ Wp2(P32T) + bias -> FP32. Grid (64 mt, 4 nt).
// ---------------------------------------------------------------------------
__global__ __launch_bounds__(256, 3) void out_gemm(const bf16* __restrict__ Ap,
                                                   const bf16* __restrict__ Wp2,
                                                   const float* __restrict__ bout,
                                                   float* __restrict__ Out) {
  int mt = blockIdx.x, nt = blockIdx.y;
  int tid = threadIdx.x;
  int wave = tid >> 6, lane = tid & 63;
  int l16 = lane & 15, quad = lane >> 4;
  int wr = wave >> 1, wc = wave & 1;

  __shared__ __align__(16) bf16 SM[16384];

  const bf16* At = Ap + (size_t)mt * 16 * 4096;
  const bf16* Bt = Wp2 + (size_t)nt * 16 * 4096;
  bf16x8 pa0 = ldg8(At + tid * 8), pa1 = ldg8(At + 2048 + tid * 8);
  bf16x8 pb0 = ldg8(Bt + tid * 8), pb1 = ldg8(Bt + 2048 + tid * 8);

  f32x4 acc[4][4] = {};
#pragma unroll 2
  for (int kc = 0; kc < 16; kc++) {
    bf16* A = SM + (kc & 1) * 4096;
    bf16* B = SM + 8192 + (kc & 1) * 4096;
    *(bf16x8*)&A[tid * 8] = pa0;
    *(bf16x8*)&A[2048 + tid * 8] = pa1;
    *(bf16x8*)&B[tid * 8] = pb0;
    *(bf16x8*)&B[2048 + tid * 8] = pb1;
    __syncthreads();
    if (kc < 15) {
      const bf16* an = At + (kc + 1) * 4096;
      const bf16* bn = Bt + (kc + 1) * 4096;
      pa0 = ldg8(an + tid * 8);
      pa1 = ldg8(an + 2048 + tid * 8);
      pb0 = ldg8(bn + tid * 8);
      pb1 = ldg8(bn + 2048 + tid * 8);
    }
    bf16x8 af[4], bfr[4];
#pragma unroll
    for (int fi = 0; fi < 4; fi++)
      af[fi] = *(const bf16x8*)&A[(quad * 128 + wr * 64 + fi * 16 + l16) * 8];
#pragma unroll
    for (int fj = 0; fj < 4; fj++)
      bfr[fj] = *(const bf16x8*)&B[(quad * 128 + wc * 64 + fj * 16 + l16) * 8];
    __builtin_amdgcn_s_setprio(1);
#pragma unroll
    for (int fi = 0; fi < 4; fi++)
#pragma unroll
      for (int fj = 0; fj < 4; fj++)
        acc[fi][fj] = MFMA16(af[fi], bfr[fj], acc[fi][fj]);
    __builtin_amdgcn_s_setprio(0);
  }

#pragma unroll
  for (int fj = 0; fj < 4; fj++) {
    int c = nt * 128 + wc * 64 + fj * 16 + l16;
    float bias = bout[c];
#pragma unroll
    for (int fi = 0; fi < 4; fi++) {
#pragma unroll
      for (int r = 0; r < 4; r++) {
        int m = mt * 128 + wr * 64 + fi * 16 + quad * 4 + r;
        Out[(size_t)m * 512 + c] = acc[fi][fj][r] + bias;
      }
    }
  }
}

// ---------------------------------------------------------------------------
// ws layout (lifetime-overlapped; end 60,293,120 < 61.4MB):
//   Q 0 (8.39M) | K 8388608 | Vt 16777216 | Wp2 25165824 (0.52M) |
//   Opart 25690112 (33.55M) | Lpart 59244544 (1.05M)
//   Wp1 34078720 (1.57M, inside Opart region, dead before flash writes it)
//   Ap 0 (overlays Q, dead post-flash; written by combine)
// ---------------------------------------------------------------------------
extern "C" void kernel_launch(void* const* d_in, const int* in_sizes, int n_in,
                              void* d_out, int out_size, void* d_ws,
                              size_t ws_size, hipStream_t stream) {
  const float* x = (const float*)d_in[0];
  const float* w_qkv = (const float*)d_in[1];
  const float* b_qkv = (const float*)d_in[2];
  const float* w_out = (const float*)d_in[3];
  const float* b_out = (const float*)d_in[4];
  float* out = (float*)d_out;

  char* ws = (char*)d_ws;
  bf16* Q = (bf16*)(ws + 0);
  bf16* K = (bf16*)(ws + 8388608);
  bf16* Vt = (bf16*)(ws + 16777216);
  bf16* Wp2 = (bf16*)(ws + 25165824);
  bf16* Opart = (bf16*)(ws + 25690112);
  float* Lpart = (float*)(ws + 59244544);
  bf16* Wp1 = (bf16*)(ws + 34078720);  // overlays Opart region, dead pre-flash
  bf16* Ap = (bf16*)(ws + 0);          // overlays Q, dead post-flash

  pack_weights<<<dim3(16, 16), 256, 0, stream>>>(w_qkv, w_out, Wp1, Wp2);
  qkv_gemm<<<dim3(64, 12), 256, 0, stream>>>(x, Wp1, b_qkv, Q, K, Vt);
  flash_partial<<<dim3(32, 16, 4), 256, 0, stream>>>(Q, K, Vt, Opart, Lpart);
  flash_combine<<<dim3(64, 16), 256, 0, stream>>>(Opart, Lpart, Ap);
  out_gemm<<<dim3(64, 4), 256, 0, stream>>>(Ap, Wp2, b_out, out);
}

// Round 7
// 191.214 us; speedup vs baseline: 1.0889x; 1.0334x over previous
//
#include <hip/hip_runtime.h>

typedef __bf16 bf16;
typedef __bf16 bf16x8 __attribute__((ext_vector_type(8)));
typedef float f32x4 __attribute__((ext_vector_type(4)));
typedef unsigned u32x4 __attribute__((ext_vector_type(4)));

#define MFMA16(a, b, c) __builtin_amdgcn_mfma_f32_16x16x32_bf16((a), (b), (c), 0, 0, 0)

static __device__ __forceinline__ bf16x8 ldg8(const bf16* p) {
  return *(const bf16x8*)p;
}
static __device__ __forceinline__ unsigned cvt_pk_bf16(float lo, float hi) {
  unsigned d;
  asm("v_cvt_pk_bf16_f32 %0, %1, %2" : "=v"(d) : "v"(lo), "v"(hi));
  return d;
}
static __device__ __forceinline__ void pl32_swap(unsigned& a, unsigned& b) {
  asm("v_permlane32_swap_b32 %0, %1" : "+v"(a), "+v"(b));
}
static __device__ __forceinline__ void pl16_swap(unsigned& a, unsigned& b) {
  asm("v_permlane16_swap_b32 %0, %1" : "+v"(a), "+v"(b));
}

// ===========================================================================
// Ladder: 803 -> ... -> 204 -> 197.6 (r6: coalesced qkv stores + fused packs).
// r6 budget closes: qkv ~30-35 (m93-class, 12 LDS ops/kstep), out ~9,
// combine ~9 (33.5MB Opart read), flash 82.5 (= m97-class ~830TF ceiling),
// gaps ~14. r7: (1) qkv B-frags DIRECT from packed global (coalesced ldg8,
// L2-resident Wp1) -> LDS ops 12->6/kstep; cvt_pk for A staging; (2)
// out_gemm 64x128 tiles, 512 blocks = 2/CU exact, A-LDS + B-direct; (3)
// flash split 4->2: same inner loop, 1024 blocks = 4/CU ONE exact fill,
// halves Q re-read + Opart traffic (combine reads 16.8 not 33.5 MB).
// ===========================================================================

// ---- pack W (fp32 [K][N]) transposed into P32T tiles: tile(nt,kc) holds
// (n,kk) at kchunk*1024 + n*8 + (kk&7). Grid (16 kc, 16 nt): nt<12 -> Wqkv
// (N=1536) else Wout (N=512, nt-12). ----
__global__ __launch_bounds__(256) void pack_weights(const float* __restrict__ Wqkv,
                                                    const float* __restrict__ Wout,
                                                    bf16* __restrict__ Wp1,
                                                    bf16* __restrict__ Wp2) {
  __shared__ float tile[32 * 129];
  int kc = blockIdx.x, nt = blockIdx.y;
  const float* W;
  bf16* dst;
  int N, ntl;
  if (nt < 12) {
    W = Wqkv; N = 1536; ntl = nt;
    dst = Wp1 + ((size_t)ntl * 16 + kc) * 4096;
  } else {
    W = Wout; N = 512; ntl = nt - 12;
    dst = Wp2 + ((size_t)ntl * 16 + kc) * 4096;
  }
  int row = threadIdx.x >> 3;
  int c0 = (threadIdx.x & 7) * 16;
  const float* src = W + (size_t)(kc * 32 + row) * N + ntl * 128 + c0;
#pragma unroll
  for (int i = 0; i < 4; i++) {
    float4 v = *(const float4*)(src + i * 4);
    tile[row * 129 + c0 + i * 4 + 0] = v.x;
    tile[row * 129 + c0 + i * 4 + 1] = v.y;
    tile[row * 129 + c0 + i * 4 + 2] = v.z;
    tile[row * 129 + c0 + i * 4 + 3] = v.w;
  }
  __syncthreads();
#pragma unroll
  for (int half = 0; half < 2; half++) {
    int U = threadIdx.x + half * 256;
    int kchunk = U >> 7, n = U & 127;
    bf16x8 o;
#pragma unroll
    for (int j = 0; j < 8; j++) o[j] = (bf16)tile[(kchunk * 8 + j) * 129 + n];
    *(bf16x8*)&dst[U * 8] = o;
  }
}

// ---------------------------------------------------------------------------
// QKV projection, 128x128 tiles. Grid (64 mt, 12 nt): nt 0-3 Q, 4-7 K,
// 8-11 V. A staged from fp32 x via cvt_pk (LDS dbuf, one-barrier);
// B-frags read DIRECTLY from packed Wp1 (coalesced ldg8, no LDS).
// LDS ops/wave/kstep: 2 write + 4 read (was 12). Epilogue: LDS round-trip
// for coalesced 16B stores (Q/K rows; V transposed to [bh][nb][d][n&63]).
// Q pre-scaled by 0.125*log2e.
// ---------------------------------------------------------------------------
__global__ __launch_bounds__(256, 3) void qkv_gemm(const float* __restrict__ x,
                                                   const bf16* __restrict__ Wp1,
                                                   const float* __restrict__ bqkv,
                                                   bf16* __restrict__ Q,
                                                   bf16* __restrict__ Kh,
                                                   bf16* __restrict__ Vt) {
  int mt = blockIdx.x, nt = blockIdx.y;
  int tid = threadIdx.x;
  int wave = tid >> 6, lane = tid & 63;
  int l16 = lane & 15, quad = lane >> 4;
  int wr = wave >> 1, wc = wave & 1;

  __shared__ __align__(16) bf16 SM[9216];  // A dbuf 2x4096; epilogue T 128x72

  int r = tid >> 1, khalf = tid & 1;
  const float* xs = x + (size_t)(mt * 128 + r) * 512 + khalf * 16;
  const bf16* Bt = Wp1 + (size_t)nt * 16 * 4096;
  int lwA0 = ((khalf * 2 + 0) * 128 + r) * 8;
  int lwA1 = ((khalf * 2 + 1) * 128 + r) * 8;

  float4 fa0 = *(const float4*)(xs + 0);
  float4 fa1 = *(const float4*)(xs + 4);
  float4 fa2 = *(const float4*)(xs + 8);
  float4 fa3 = *(const float4*)(xs + 12);

  f32x4 acc[4][4] = {};
#pragma unroll 2
  for (int kc = 0; kc < 16; kc++) {
    bf16* A = SM + (kc & 1) * 4096;
    u32x4 pk0 = {cvt_pk_bf16(fa0.x, fa0.y), cvt_pk_bf16(fa0.z, fa0.w),
                 cvt_pk_bf16(fa1.x, fa1.y), cvt_pk_bf16(fa1.z, fa1.w)};
    u32x4 pk1 = {cvt_pk_bf16(fa2.x, fa2.y), cvt_pk_bf16(fa2.z, fa2.w),
                 cvt_pk_bf16(fa3.x, fa3.y), cvt_pk_bf16(fa3.z, fa3.w)};
    *(bf16x8*)&A[lwA0] = __builtin_bit_cast(bf16x8, pk0);
    *(bf16x8*)&A[lwA1] = __builtin_bit_cast(bf16x8, pk1);
    __syncthreads();
    if (kc < 15) {
      const float* xn = xs + (kc + 1) * 32;
      fa0 = *(const float4*)(xn + 0);
      fa1 = *(const float4*)(xn + 4);
      fa2 = *(const float4*)(xn + 8);
      fa3 = *(const float4*)(xn + 12);
    }
    bf16x8 af[4], bfr[4];
#pragma unroll
    for (int fi = 0; fi < 4; fi++)
      af[fi] = *(const bf16x8*)&A[(quad * 128 + wr * 64 + fi * 16 + l16) * 8];
    const bf16* Bk = Bt + kc * 4096;
#pragma unroll
    for (int fj = 0; fj < 4; fj++)
      bfr[fj] = ldg8(Bk + (quad * 128 + wc * 64 + fj * 16 + l16) * 8);
    __builtin_amdgcn_s_setprio(1);
#pragma unroll
    for (int fi = 0; fi < 4; fi++)
#pragma unroll
      for (int fj = 0; fj < 4; fj++)
        acc[fi][fj] = MFMA16(af[fi], bfr[fj], acc[fi][fj]);
    __builtin_amdgcn_s_setprio(0);
  }

  // ---- epilogue: LDS round-trip, coalesced 16B stores ----
  __syncthreads();  // all frag reads done before SM reuse
  const int TS = 72;
  int b = mt >> 5;

  if (nt < 8) {
    bool isQ = nt < 4;
    bf16* dstb = isQ ? Q : Kh;
    int hb = isQ ? nt * 2 : (nt - 4) * 2;
#pragma unroll
    for (int ph = 0; ph < 2; ph++) {
      if (wc == ph) {
#pragma unroll
        for (int fj = 0; fj < 4; fj++) {
          float bias = bqkv[nt * 128 + wc * 64 + fj * 16 + l16];
#pragma unroll
          for (int fi = 0; fi < 4; fi++)
#pragma unroll
            for (int rr = 0; rr < 4; rr++) {
              float v = acc[fi][fj][rr] + bias;
              if (isQ) v *= 0.18033688f;  // 0.125*log2e
              SM[(wr * 64 + fi * 16 + quad * 4 + rr) * TS + fj * 16 + l16] =
                  (bf16)v;
            }
        }
      }
      __syncthreads();
      int bh = b * 8 + hb + ph;
      bf16* dh = dstb + (size_t)bh * 4096 * 64 + (size_t)((mt & 31) * 128) * 64;
#pragma unroll
      for (int i = 0; i < 4; i++) {
        int U = tid + i * 256;
        int mr = U >> 3, oct = U & 7;
        bf16x8 v = ldg8(&SM[mr * TS + oct * 8]);
        *(bf16x8*)&dh[(size_t)mr * 64 + oct * 8] = v;
      }
      __syncthreads();
    }
  } else {
    int h0 = (nt - 8) * 2;
#pragma unroll
    for (int ph = 0; ph < 2; ph++) {
      if (wr == ph) {
#pragma unroll
        for (int fj = 0; fj < 4; fj++) {
          float bias = bqkv[nt * 128 + wc * 64 + fj * 16 + l16];
          int cp = wc * 64 + fj * 16 + l16;
#pragma unroll
          for (int fi = 0; fi < 4; fi++)
#pragma unroll
            for (int rr = 0; rr < 4; rr++)
              SM[cp * TS + fi * 16 + quad * 4 + rr] =
                  (bf16)(acc[fi][fj][rr] + bias);
        }
      }
      __syncthreads();
      int nb = (mt & 31) * 2 + ph;
#pragma unroll
      for (int i = 0; i < 4; i++) {
        int U = tid + i * 256;
        int cp = U >> 3, oct = U & 7;
        int h = h0 + (cp >> 6), d = cp & 63;
        int bh = b * 8 + h;
        bf16x8 v = ldg8(&SM[cp * TS + oct * 8]);
        *(bf16x8*)&Vt[(((size_t)bh * 64 + nb) * 64 + d) * 64 + oct * 8] = v;
      }
      __syncthreads();
    }
  }
}

// ---------------------------------------------------------------------------
// flash_partial (r2/r5-proven inner loop): grid (32 strip128, 16 bh, 2 half)
// = 1024 blocks = exactly 4/CU, ONE fill. 4 waves, 32 Q rows/wave, 32
// KV-tiles of 64. Per-h2 clusters: QK(8 MFMA) -> SM -> PV+l(10 MFMA).
// In-reg P (cvt_pk+permlane), exp2, ones-MFMA rowsum. K/V dbuf, ONE
// barrier/tile, reg-prefetch after barrier.
// ---------------------------------------------------------------------------
__global__ __launch_bounds__(256, 4) void flash_partial(const bf16* __restrict__ Q,
                                                        const bf16* __restrict__ K,
                                                        const bf16* __restrict__ Vt,
                                                        bf16* __restrict__ Opart,
                                                        float* __restrict__ Lpart) {
  int strip = blockIdx.x, bh = blockIdx.y, half = blockIdx.z;
  int tid = threadIdx.x;
  int wave = tid >> 6, lane = tid & 63;
  int l16 = lane & 15, quad = lane >> 4;

  const bf16* Qh = Q + (size_t)bh * 4096 * 64;
  const bf16* Kg = K + ((size_t)bh * 4096 + half * 2048) * 64;
  const bf16* Vg = Vt + (size_t)bh * 64 * 4096 + (size_t)half * 2048 * 64;

  __shared__ __align__(16) bf16 Klds[2][4096];
  __shared__ __align__(16) bf16 Vlds[2][4096];

  int qbase = strip * 128 + wave * 32;
  bf16x8 aq[2][2];
#pragma unroll
  for (int mt = 0; mt < 2; mt++) {
    const bf16* qr = Qh + (size_t)(qbase + mt * 16 + l16) * 64;
    aq[mt][0] = ldg8(qr + quad * 8);
    aq[mt][1] = ldg8(qr + 32 + quad * 8);
  }

  bf16x8 ones;
#pragma unroll
  for (int i = 0; i < 8; i++) ones[i] = (bf16)1.0f;

  f32x4 o[2][4] = {};
  f32x4 acc_l[2] = {};

  int e0 = tid * 8, e1 = (256 + tid) * 8;
  int r0 = e0 >> 6, r1 = e1 >> 6;
  int u0 = r0 * 8 + (((e0 & 63) >> 3) ^ (r0 & 7));
  int u1 = r1 * 8 + (((e1 & 63) >> 3) ^ (r1 & 7));

  bf16x8 kp0 = ldg8(Kg + e0), kp1 = ldg8(Kg + e1);
  bf16x8 vp0 = ldg8(Vg + e0), vp1 = ldg8(Vg + e1);

#pragma unroll 2
  for (int t = 0; t < 32; t++) {
    int cur = t & 1;
    bf16* kl = Klds[cur];
    bf16* vl = Vlds[cur];
    *(bf16x8*)&kl[u0 * 8] = kp0;
    *(bf16x8*)&kl[u1 * 8] = kp1;
    *(bf16x8*)&vl[u0 * 8] = vp0;
    *(bf16x8*)&vl[u1 * 8] = vp1;
    __syncthreads();

    if (t < 31) {
      const bf16* kg = Kg + (size_t)(t + 1) * 4096;
      const bf16* vg = Vg + (size_t)(t + 1) * 4096;
      kp0 = ldg8(kg + e0);
      kp1 = ldg8(kg + e1);
      vp0 = ldg8(vg + e0);
      vp1 = ldg8(vg + e1);
    }

#pragma unroll
    for (int h2 = 0; h2 < 2; h2++) {
      f32x4 s[2][2] = {};
      __builtin_amdgcn_s_setprio(1);
#pragma unroll
      for (int c2 = 0; c2 < 2; c2++) {
        int n = h2 * 32 + c2 * 16 + l16;
        bf16x8 k0 = *(const bf16x8*)&kl[(n * 8 + (quad ^ (n & 7))) * 8];
        bf16x8 k1 = *(const bf16x8*)&kl[(n * 8 + ((4 + quad) ^ (n & 7))) * 8];
#pragma unroll
        for (int mt = 0; mt < 2; mt++) {
          s[mt][c2] = MFMA16(k0, aq[mt][0], s[mt][c2]);
          s[mt][c2] = MFMA16(k1, aq[mt][1], s[mt][c2]);
        }
      }
      __builtin_amdgcn_s_setprio(0);

      bf16x8 pa[2];
#pragma unroll
      for (int mt = 0; mt < 2; mt++) {
        unsigned ue[2], wo[2];
#pragma unroll
        for (int c2 = 0; c2 < 2; c2++) {
          float p0 = __builtin_amdgcn_exp2f(s[mt][c2][0]);
          float p1 = __builtin_amdgcn_exp2f(s[mt][c2][1]);
          float p2 = __builtin_amdgcn_exp2f(s[mt][c2][2]);
          float p3 = __builtin_amdgcn_exp2f(s[mt][c2][3]);
          ue[c2] = cvt_pk_bf16(p0, p1);
          wo[c2] = cvt_pk_bf16(p2, p3);
        }
        pl32_swap(ue[0], ue[1]);
        pl16_swap(ue[0], ue[1]);
        pl32_swap(wo[0], wo[1]);
        pl16_swap(wo[0], wo[1]);
        u32x4 pk = {ue[0], wo[0], ue[1], wo[1]};
        pa[mt] = __builtin_bit_cast(bf16x8, pk);
      }

      __builtin_amdgcn_s_setprio(1);
      acc_l[0] = MFMA16(pa[0], ones, acc_l[0]);
      acc_l[1] = MFMA16(pa[1], ones, acc_l[1]);
#pragma unroll
      for (int ct = 0; ct < 4; ct++) {
        int d = ct * 16 + l16;
        bf16x8 bv = *(const bf16x8*)&vl[(d * 8 + ((h2 * 4 + quad) ^ (d & 7))) * 8];
        o[0][ct] = MFMA16(pa[0], bv, o[0][ct]);
        o[1][ct] = MFMA16(pa[1], bv, o[1][ct]);
      }
      __builtin_amdgcn_s_setprio(0);
    }
  }

  size_t ub = ((size_t)half * 16 + bh) * 32 + strip;
  bf16* op = Opart + ub * 8192;
#pragma unroll
  for (int mt = 0; mt < 2; mt++) {
#pragma unroll
    for (int ct = 0; ct < 4; ct++)
#pragma unroll
      for (int r = 0; r < 4; r++)
        op[(wave * 32 + mt * 16 + quad * 4 + r) * 64 + ct * 16 + l16] =
            (bf16)o[mt][ct][r];
    if (l16 == 0) {
#pragma unroll
      for (int r = 0; r < 4; r++)
        Lpart[ub * 128 + wave * 32 + mt * 16 + quad * 4 + r] = acc_l[mt][r];
    }
  }
}

// ---------------------------------------------------------------------------
// flash_combine: Ap(P32-packed) = (o0+o1)/(l0+l1). Grid (64 mt, 16 kc).
// ---------------------------------------------------------------------------
__global__ __launch_bounds__(256) void flash_combine(const bf16* __restrict__ Opart,
                                                     const float* __restrict__ Lpart,
                                                     bf16* __restrict__ Ap) {
  int mt = blockIdx.x, kc = blockIdx.y;
  int b = mt >> 5, strip = mt & 31;
  int h = kc >> 1, d0 = (kc & 1) * 32;
  int bh = b * 8 + h;
  size_t u0 = (size_t)bh * 32 + strip;
  size_t u1 = ((size_t)16 + bh) * 32 + strip;
  bf16* dst = Ap + ((size_t)mt * 16 + kc) * 4096;
#pragma unroll
  for (int hf = 0; hf < 2; hf++) {
    int U = threadIdx.x + hf * 256;
    int kchunk = U >> 7, r = U & 127;
    bf16x8 o0 = ldg8(&Opart[u0 * 8192 + r * 64 + d0 + kchunk * 8]);
    bf16x8 o1 = ldg8(&Opart[u1 * 8192 + r * 64 + d0 + kchunk * 8]);
    float ls = Lpart[u0 * 128 + r] + Lpart[u1 * 128 + r];
    float rl = 1.0f / ls;
    bf16x8 ov;
#pragma unroll
    for (int j = 0; j < 8; j++)
      ov[j] = (bf16)(((float)o0[j] + (float)o1[j]) * rl);
    *(bf16x8*)&dst[U * 8] = ov;
  }
}

// ---------------------------------------------------------------------------
// Output projection: 64x128 tiles, grid (128 mt, 4 nt) = 512 blocks = 2/CU.
// A (64x32 subtile of P32 Ap) staged via LDS dbuf (one barrier); B-frags
// direct coalesced ldg8 from L2-resident Wp2. Per wave/kstep: 1+2 ldg8,
// 1 ds_write + 4 ds_read, 8 MFMA. acc[4][2] = 32 VGPR.
// ---------------------------------------------------------------------------
__global__ __launch_bounds__(256, 4) void out_gemm(const bf16* __restrict__ Ap,
                                                   const bf16* __restrict__ Wp2,
                                                   const float* __restrict__ bout,
                                                   float* __restrict__ Out) {
  int mt = blockIdx.x, nt = blockIdx.y;
  int tid = threadIdx.x;
  int wave = tid >> 6, lane = tid & 63;
  int l16 = lane & 15, quad = lane >> 4;
  int mt128 = mt >> 1, mhalf = mt & 1;

  __shared__ __align__(16) bf16 SM[2][2048];

  const bf16* At = Ap + (size_t)mt128 * 16 * 4096;
  const bf16* Bt = Wp2 + (size_t)nt * 16 * 4096;
  int guni = (tid >> 6) * 128 + mhalf * 64 + (tid & 63);  // global unit in tile

  bf16x8 pa = ldg8(At + guni * 8);
  f32x4 acc[4][2] = {};
#pragma unroll 2
  for (int kc = 0; kc < 16; kc++) {
    bf16* A = SM[kc & 1];
    *(bf16x8*)&A[tid * 8] = pa;
    __syncthreads();
    if (kc < 15) pa = ldg8(At + (kc + 1) * 4096 + guni * 8);
    bf16x8 af[4], bfr[2];
#pragma unroll
    for (int fi = 0; fi < 4; fi++)
      af[fi] = *(const bf16x8*)&A[(quad * 64 + fi * 16 + l16) * 8];
    const bf16* Bk = Bt + kc * 4096;
#pragma unroll
    for (int fj = 0; fj < 2; fj++)
      bfr[fj] = ldg8(Bk + (quad * 128 + wave * 32 + fj * 16 + l16) * 8);
    __builtin_amdgcn_s_setprio(1);
#pragma unroll
    for (int fi = 0; fi < 4; fi++)
#pragma unroll
      for (int fj = 0; fj < 2; fj++)
        acc[fi][fj] = MFMA16(af[fi], bfr[fj], acc[fi][fj]);
    __builtin_amdgcn_s_setprio(0);
  }

#pragma unroll
  for (int fj = 0; fj < 2; fj++) {
    int c = nt * 128 + wave * 32 + fj * 16 + l16;
    float bias = bout[c];
#pragma unroll
    for (int fi = 0; fi < 4; fi++) {
#pragma unroll
      for (int r = 0; r < 4; r++) {
        int m = mt * 64 + fi * 16 + quad * 4 + r;
        Out[(size_t)m * 512 + c] = acc[fi][fj][r] + bias;
      }
    }
  }
}

// ---------------------------------------------------------------------------
// ws layout (no overlays needed except Ap->Q; end 44,564,480 < 61.4MB):
//   Q 0 (8.39M) | K 8388608 | Vt 16777216 | Wp2 25165824 (0.52M) |
//   Opart 25690112 (16.78M) | Lpart 42467328 (0.52M) | Wp1 42991616 (1.57M)
//   Ap 0 (overlays Q, dead post-flash; written by combine)
// ---------------------------------------------------------------------------
extern "C" void kernel_launch(void* const* d_in, const int* in_sizes, int n_in,
                              void* d_out, int out_size, void* d_ws,
                              size_t ws_size, hipStream_t stream) {
  const float* x = (const float*)d_in[0];
  const float* w_qkv = (const float*)d_in[1];
  const float* b_qkv = (const float*)d_in[2];
  const float* w_out = (const float*)d_in[3];
  const float* b_out = (const float*)d_in[4];
  float* out = (float*)d_out;

  char* ws = (char*)d_ws;
  bf16* Q = (bf16*)(ws + 0);
  bf16* K = (bf16*)(ws + 8388608);
  bf16* Vt = (bf16*)(ws + 16777216);
  bf16* Wp2 = (bf16*)(ws + 25165824);
  bf16* Opart = (bf16*)(ws + 25690112);
  float* Lpart = (float*)(ws + 42467328);
  bf16* Wp1 = (bf16*)(ws + 42991616);
  bf16* Ap = (bf16*)(ws + 0);  // overlays Q, dead post-flash

  pack_weights<<<dim3(16, 16), 256, 0, stream>>>(w_qkv, w_out, Wp1, Wp2);
  qkv_gemm<<<dim3(64, 12), 256, 0, stream>>>(x, Wp1, b_qkv, Q, K, Vt);
  flash_partial<<<dim3(32, 16, 2), 256, 0, stream>>>(Q, K, Vt, Opart, Lpart);
  flash_combine<<<dim3(64, 16), 256, 0, stream>>>(Opart, Lpart, Ap);
  out_gemm<<<dim3(128, 4), 256, 0, stream>>>(Ap, Wp2, b_out, out);
}